// Round 9
// baseline (780.263 us; speedup 1.0000x reference)
//
#include <hip/hip_runtime.h>
#include <hip/hip_bf16.h>
#include <stdint.h>

#define B_  2048
#define T_  16
#define F_  768
#define H_  1024
#define G4_ 4096   // 4*H

typedef __attribute__((ext_vector_type(8))) __bf16 bf16x8;
typedef __attribute__((ext_vector_type(4))) float  f32x4;

static __device__ __forceinline__ unsigned short f2bf(float f) {
    union { float f; uint32_t u; } v; v.f = f;
    uint32_t u = v.u;
    uint32_t r = (u + 0x7fffu + ((u >> 16) & 1u)) >> 16;   // RNE
    return (unsigned short)r;
}
static __device__ __forceinline__ unsigned short f2h(float f) {
    union { _Float16 h; unsigned short u; } v; v.h = (_Float16)f; return v.u;
}
static __device__ __forceinline__ float h2f(unsigned short u) {
    union { _Float16 h; unsigned short u; } v; v.u = u; return (float)v.h;
}
static __device__ __forceinline__ float sigf(float x) {
    return 1.0f / (1.0f + __expf(-x));
}
static __device__ __forceinline__ float tanhfast(float x) {
    return 2.0f / (1.0f + __expf(-2.0f * x)) - 1.0f;
}

#define GLOAD_LDS16(gsrc, ldst)                                                       \
    __builtin_amdgcn_global_load_lds((const __attribute__((address_space(1))) void*)(gsrc), \
                                     (__attribute__((address_space(3))) void*)(ldst), \
                                     16, 0, 0)

// ---------------------------------------------------------------- prep kernels

__global__ void convert_x_kernel(const float* __restrict__ x,
                                 unsigned short* __restrict__ xbf, int n4) {
    int idx = blockIdx.x * blockDim.x + threadIdx.x;
    if (idx >= n4) return;
    float4 v = *(const float4*)(x + (size_t)idx * 4);
    ushort4 o;
    o.x = f2bf(v.x); o.y = f2bf(v.y); o.z = f2bf(v.z); o.w = f2bf(v.w);
    *(ushort4*)(xbf + (size_t)idx * 4) = o;
}

// W [K][4096] f32 -> Wt_perm [4096][K] bf16, gate-interleaved.
// mode 0 (Wih, 256-col tiles):  n' = (j>>6)*256 + g*64 + ((j>>4)&3)*16 + (j&15)
// mode 1 (Whh, 64-col blocks):  n' = (j>>4)*64  + g*16 + (j&15)
__global__ void transpose_w_kernel(const float* __restrict__ w,
                                   unsigned short* __restrict__ wt, int K, int mode) {
    __shared__ float tile[32][33];
    int nb = blockIdx.x * 32;
    int kb = blockIdx.y * 32;
    int tx = threadIdx.x, ty = threadIdx.y;
    #pragma unroll
    for (int i = 0; i < 32; i += 8)
        tile[ty + i][tx] = w[(size_t)(kb + ty + i) * G4_ + nb + tx];
    __syncthreads();
    #pragma unroll
    for (int i = 0; i < 32; i += 8) {
        int n = nb + ty + i;
        int g = n >> 10;
        int j = n & 1023;
        int np = mode ? ((j >> 4) * 64 + g * 16 + (j & 15))
                      : ((j >> 6) * 256 + g * 64 + ((j >> 4) & 3) * 16 + (j & 15));
        wt[(size_t)np * K + kb + tx] = f2bf(tile[tx][ty + i]);
    }
}

// ================================================================ 8-phase 256^2 xgemm
// (round-4 kernel verbatim; proven 219 us, MfmaUtil 41%)

#define STAGE4(bufi, kind, half, gbase, ld, rowbase, kt) do {                         \
    const int kel_ = (kt) * 64;                                                       \
    _Pragma("unroll")                                                                 \
    for (int r2 = 0; r2 < 2; ++r2) {                                                  \
        const int rih_ = r2 * 64 + (tid >> 3);                                        \
        const int ch_  = (tid & 7) ^ (rih_ & 7);                                      \
        GLOAD_LDS16((gbase) + (size_t)((rowbase) + (half) * 128 + rih_) * (ld)        \
                            + kel_ + ch_ * 8,                                         \
                    &lds[bufi][kind][half][r2 * 4096 + tid * 8]);                     \
    }                                                                                 \
} while (0)

#define RD4_A(half_, mb)                                                              \
    _Pragma("unroll")                                                                 \
    for (int mm = 0; mm < 4; ++mm) {                                                  \
        const int row_ = ((mb) + mm) * 32 + wm * 16 + fr;                             \
        _Pragma("unroll")                                                             \
        for (int kk = 0; kk < 2; ++kk)                                                \
            Afr[mm][kk] = *(const bf16x8*)&lds[buf][0][half_]                         \
                [(row_ & 127) * 64 + (((kk * 4 + fq) ^ (row_ & 7)) * 8)];             \
    }

#define RD4_B(half_, nb)                                                              \
    _Pragma("unroll")                                                                 \
    for (int nn = 0; nn < 2; ++nn) {                                                  \
        const int row_ = ((nb) + nn) * 64 + wn * 16 + fr;                             \
        _Pragma("unroll")                                                             \
        for (int kk = 0; kk < 2; ++kk)                                                \
            Bfr[(nb) + nn][kk] = *(const bf16x8*)&lds[buf][1][half_]                  \
                [(row_ & 127) * 64 + (((kk * 4 + fq) ^ (row_ & 7)) * 8)];             \
    }

#define MFMAQ(mb, nb)                                                                 \
    __builtin_amdgcn_s_setprio(1);                                                    \
    _Pragma("unroll")                                                                 \
    for (int mm = 0; mm < 4; ++mm)                                                    \
        _Pragma("unroll")                                                             \
        for (int nn = 0; nn < 2; ++nn)                                                \
            _Pragma("unroll")                                                         \
            for (int kk = 0; kk < 2; ++kk)                                            \
                acc[(mb) + mm][(nb) + nn] = __builtin_amdgcn_mfma_f32_16x16x32_bf16(  \
                    Afr[mm][kk], Bfr[(nb) + nn][kk], acc[(mb) + mm][(nb) + nn], 0, 0, 0); \
    __builtin_amdgcn_s_setprio(0);

#define WAITV4  asm volatile("s_waitcnt vmcnt(10)" ::: "memory");                     \
                __builtin_amdgcn_sched_barrier(0);
#define BARR4   __builtin_amdgcn_s_barrier();                                         \
                __builtin_amdgcn_sched_barrier(0);

#define KLOOP4(ABASE, ALD, BBASE, BLD, NT)                                            \
    STAGE4(0, 0, 0, ABASE, ALD, bm0, 0);                                              \
    STAGE4(0, 1, 0, BBASE, BLD, bn0, 0);                                              \
    STAGE4(0, 1, 1, BBASE, BLD, bn0, 0);                                              \
    STAGE4(0, 0, 1, ABASE, ALD, bm0, 0);                                              \
    STAGE4(1, 0, 0, ABASE, ALD, bm0, 1);                                              \
    STAGE4(1, 1, 0, BBASE, BLD, bn0, 1);                                              \
    STAGE4(1, 1, 1, BBASE, BLD, bn0, 1);                                              \
    WAITV4; BARR4;                                                                    \
    for (int kt = 0; kt < (NT); ++kt) {                                               \
        const int buf = kt & 1, nbuf = buf ^ 1;                                       \
        const int k1 = (kt + 1 < (NT)) ? kt + 1 : (NT) - 1;                           \
        const int k2 = (kt + 2 < (NT)) ? kt + 2 : (NT) - 1;                           \
        bf16x8 Afr[4][2]; bf16x8 Bfr[4][2];                                           \
        /* ph0 */                                                                     \
        RD4_A(0, 0); RD4_B(0, 0);                                                     \
        STAGE4(nbuf, 0, 1, ABASE, ALD, bm0, k1);                                      \
        WAITV4; BARR4;                                                                \
        MFMAQ(0, 0); BARR4;                                                           \
        /* ph1 */                                                                     \
        RD4_B(1, 2);                                                                  \
        STAGE4(buf, 0, 0, ABASE, ALD, bm0, k2);                                       \
        WAITV4; BARR4;                                                                \
        MFMAQ(0, 2); BARR4;                                                           \
        /* ph2 */                                                                     \
        RD4_A(1, 4);                                                                  \
        STAGE4(buf, 1, 0, BBASE, BLD, bn0, k2);                                       \
        BARR4;                                                                        \
        MFMAQ(4, 0); BARR4;                                                           \
        /* ph3 */                                                                     \
        STAGE4(buf, 1, 1, BBASE, BLD, bn0, k2);                                       \
        WAITV4; BARR4;                                                                \
        MFMAQ(4, 2); BARR4;                                                           \
    }

__global__ __launch_bounds__(512, 2) void xgemm8_kernel(
        const unsigned short* __restrict__ xbf,    // [32768][768] bf16 (m = b*16+t)
        const unsigned short* __restrict__ wih_t,  // [4096][768]  bf16 perm mode0
        unsigned short* __restrict__ gx) {         // [16][2048][1024][4] f16
    __shared__ __align__(16) unsigned short lds[2][2][2][8192];   // 128 KB

    const int bid = blockIdx.x;
    const int xcd = bid & 7;
    const int i   = bid >> 3;            // 0..255
    const int bmg = i >> 6;              // 0..3
    const int r   = i & 63;
    const int bn  = r >> 2;              // 0..15
    const int bm  = xcd * 16 + bmg * 4 + (r & 3);   // 0..127
    const int bm0 = bm * 256, bn0 = bn * 256;

    const int tid = threadIdx.x;
    const int wid = tid >> 6, lane = tid & 63;
    const int wm = wid >> 2, wn = wid & 3;
    const int fr = lane & 15, fq = lane >> 4;

    f32x4 acc[8][4] = {};

    KLOOP4(xbf, F_, wih_t, F_, 12)

    const int j = bn * 64 + wn * 16 + fr;
    #pragma unroll
    for (int mm = 0; mm < 8; ++mm) {
        #pragma unroll
        for (int rr = 0; rr < 4; ++rr) {
            int row = bm0 + mm * 32 + wm * 16 + fq * 4 + rr;
            int tt = row & 15, bb = row >> 4;
            ushort4 o;
            o.x = f2h(acc[mm][0][rr]);
            o.y = f2h(acc[mm][1][rr]);
            o.z = f2h(acc[mm][2][rr]);
            o.w = f2h(acc[mm][3][rr]);
            *(ushort4*)(gx + (((size_t)tt * B_ + bb) * H_ + j) * 4) = o;
        }
    }
}

// ================================================================ recurrent step
// BM=64, BN=128, BK=64, 256 thr = 4 waves (2m x 2n), wave tile 32x64.
//   m-frag mm (0..1): row = wm*32 + mm*16 + fr
//   n-frag nf (0..3): col = wn*64 + nf*16 + fr   (nf == gate, mode-1 W perm)
// LDS 72KB: A[3][64][64], B[3][128][64]; slot(kt)=kt%3 -> 2 blocks/CU.
// Single-phase per K-tile (count-identical to round-8's verified schedule):
//   { 12 ds_read(kt) | 6 gload_lds(kt+2 -> slot (kt+2)%3)
//     | lgkmcnt(0) | 16 MFMA | vmcnt(6) | s_barrier }
// Liveness: stage target slot's readers retired >=1 barrier earlier; read
// slot's stage forced complete by the vmcnt(6) every wave executed before the
// previous barrier (12 outstanding -> keep newest 6). vmcnt never 0 (T4).

#define STAGE_A6(slot, kt) do {                                                       \
    const int kel_ = (kt) * 64;                                                       \
    _Pragma("unroll")                                                                 \
    for (int r2 = 0; r2 < 2; ++r2) {                                                  \
        const int rih_ = r2 * 32 + (tid >> 3);                                        \
        const int ch_  = (tid & 7) ^ (rih_ & 7);                                      \
        GLOAD_LDS16(SRC_A + (size_t)(bm0 + rih_) * H_ + kel_ + ch_ * 8,               \
                    &ldsA[slot][r2 * 2048 + tid * 8]);                                \
    }                                                                                 \
} while (0)

#define STAGE_B6(slot, kt) do {                                                       \
    const int kel_ = (kt) * 64;                                                       \
    _Pragma("unroll")                                                                 \
    for (int r4 = 0; r4 < 4; ++r4) {                                                  \
        const int rih_ = r4 * 32 + (tid >> 3);                                        \
        const int ch_  = (tid & 7) ^ (rih_ & 7);                                      \
        GLOAD_LDS16(SRC_B + (size_t)(bn0 + rih_) * H_ + kel_ + ch_ * 8,               \
                    &ldsB[slot][r4 * 2048 + tid * 8]);                                \
    }                                                                                 \
} while (0)

#define RD_A6(slot, AR)                                                               \
    _Pragma("unroll")                                                                 \
    for (int mm = 0; mm < 2; ++mm) {                                                  \
        const int row_ = wm * 32 + mm * 16 + fr;                                      \
        _Pragma("unroll")                                                             \
        for (int kk = 0; kk < 2; ++kk)                                                \
            AR[mm][kk] = *(const bf16x8*)&ldsA[slot]                                  \
                [row_ * 64 + (((kk * 4 + fq) ^ (row_ & 7)) * 8)];                     \
    }

#define RD_B6(slot, BF)                                                               \
    _Pragma("unroll")                                                                 \
    for (int nf = 0; nf < 4; ++nf) {                                                  \
        const int rowb_ = wn * 64 + nf * 16 + fr;                                     \
        _Pragma("unroll")                                                             \
        for (int kk = 0; kk < 2; ++kk)                                                \
            BF[nf][kk] = *(const bf16x8*)&ldsB[slot]                                  \
                [rowb_ * 64 + (((kk * 4 + fq) ^ (rowb_ & 7)) * 8)];                   \
    }

#define MFMA16S(AR, BF)                                                               \
    __builtin_amdgcn_s_setprio(1);                                                    \
    _Pragma("unroll")                                                                 \
    for (int mm = 0; mm < 2; ++mm)                                                    \
        _Pragma("unroll")                                                             \
        for (int nf = 0; nf < 4; ++nf)                                                \
            _Pragma("unroll")                                                         \
            for (int kk = 0; kk < 2; ++kk)                                            \
                acc[mm][nf] = __builtin_amdgcn_mfma_f32_16x16x32_bf16(                \
                    AR[mm][kk], BF[nf][kk], acc[mm][nf], 0, 0, 0);                    \
    __builtin_amdgcn_s_setprio(0);

#define WAIT6 asm volatile("s_waitcnt vmcnt(6)" ::: "memory");
#define LGKM0 asm volatile("s_waitcnt lgkmcnt(0)" ::: "memory");
#define BARR  __builtin_amdgcn_s_barrier();

#define KTILE6(KT, NT) do {                                                           \
    const int s_  = (KT) % 3;                                                         \
    const int s2_ = ((KT) + 2) % 3;                                                   \
    const int k2_ = ((KT) + 2 < (NT)) ? (KT) + 2 : (NT) - 1;                          \
    bf16x8 Am[2][2], Bf[4][2];                                                        \
    RD_A6(s_, Am);                                                                    \
    RD_B6(s_, Bf);                                                                    \
    STAGE_A6(s2_, k2_);                                                               \
    STAGE_B6(s2_, k2_);                                                               \
    LGKM0;                                                                            \
    MFMA16S(Am, Bf);                                                                  \
    WAIT6; BARR;                                                                      \
} while (0)

__global__ __launch_bounds__(256, 2) void lstm_step6_kernel(
        const unsigned short* __restrict__ hprev,  // [2048][1024] bf16
        const unsigned short* __restrict__ whh_t,  // [4096][1024] bf16 perm mode1
        const unsigned short* __restrict__ gx,     // [16][2048][1024][4] f16
        const float* __restrict__ bias,            // [4096] original order
        float* __restrict__ c,                     // [2048][1024] f32 r/w
        unsigned short* __restrict__ hnext,        // [2048][1024] bf16
        float* __restrict__ hout,                  // [2048][1024] f32 (last)
        int t, int last) {
    __shared__ __align__(16) unsigned short ldsA[3][4096];   // 24 KB
    __shared__ __align__(16) unsigned short ldsB[3][8192];   // 48 KB

    // XCD-aware: xcd owns bn group of 4 -> Whh panel 1MB L2-resident
    const int bid = blockIdx.x;
    const int xcd = bid & 7;
    const int i   = bid >> 3;                 // 0..127
    const int bn  = xcd * 4 + (i & 3);        // 0..31
    const int bm  = i >> 2;                   // 0..31
    const int bm0 = bm * 64, bn0 = bn * 128;

    const int tid = threadIdx.x;
    const int wid = tid >> 6, lane = tid & 63;
    const int wm = wid >> 1, wn = wid & 1;
    const int fr = lane & 15, fq = lane >> 4;

    const unsigned short* __restrict__ SRC_A = hprev;
    const unsigned short* __restrict__ SRC_B = whh_t;

    f32x4 acc[2][4] = {};

    // prologue: tiles 0 and 1 (12 loads); WAIT6 forces tile-0 landed
    STAGE_A6(0, 0); STAGE_B6(0, 0);
    STAGE_A6(1, 1); STAGE_B6(1, 1);
    WAIT6; BARR;

    for (int kt = 0; kt < 16; ++kt) KTILE6(kt, 16);

    // fused LSTM-cell epilogue; unit j = (bn*2 + wn)*16 + fr, gate = nf
    const int j = (bn * 2 + wn) * 16 + fr;
    const float b_i = bias[j];
    const float b_f = bias[H_ + j];
    const float b_g = bias[2 * H_ + j];
    const float b_o = bias[3 * H_ + j];

    #pragma unroll
    for (int mm = 0; mm < 2; ++mm) {
        #pragma unroll
        for (int rr = 0; rr < 4; ++rr) {
            int row = bm0 + wm * 32 + mm * 16 + fq * 4 + rr;
            ushort4 g4 = *(const ushort4*)(gx + (((size_t)t * B_ + row) * H_ + j) * 4);
            float gi = acc[mm][0][rr] + b_i + h2f(g4.x);
            float gf = acc[mm][1][rr] + b_f + h2f(g4.y);
            float gg = acc[mm][2][rr] + b_g + h2f(g4.z);
            float go = acc[mm][3][rr] + b_o + h2f(g4.w);
            size_t off = (size_t)row * H_ + j;
            float cold = c[off];
            float cn = sigf(gf) * cold + sigf(gi) * tanhfast(gg);
            float hv = sigf(go) * tanhfast(cn);
            c[off] = cn;
            hnext[off] = f2bf(hv);
            if (last) hout[off] = hv;
        }
    }
}

// ---------------------------------------------------------------- t=0 cell (no h/c input)

__global__ void cell0_kernel(const unsigned short* __restrict__ gx,   // [16][2048][1024][4]
                             const float* __restrict__ bias,
                             float* __restrict__ c,
                             unsigned short* __restrict__ hbf) {
    int idx = blockIdx.x * blockDim.x + threadIdx.x;   // 0 .. B*H-1
    int b = idx >> 10;
    int j = idx & 1023;
    ushort4 g4 = *(const ushort4*)(gx + ((size_t)b * H_ + j) * 4);   // t=0 slice
    float gi = bias[j]          + h2f(g4.x);
    float gg = bias[2 * H_ + j] + h2f(g4.z);
    float go = bias[3 * H_ + j] + h2f(g4.w);
    float cn = sigf(gi) * tanhfast(gg);                // c_old = 0
    float hv = sigf(go) * tanhfast(cn);
    size_t off = (size_t)b * H_ + j;
    c[off] = cn;
    hbf[off] = f2bf(hv);
}

// ---------------------------------------------------------------- launch

extern "C" void kernel_launch(void* const* d_in, const int* in_sizes, int n_in,
                              void* d_out, int out_size, void* d_ws, size_t ws_size,
                              hipStream_t stream) {
    const float* x    = (const float*)d_in[0];   // [B,T,F]
    const float* Wih  = (const float*)d_in[1];   // [F,4H]
    const float* Whh  = (const float*)d_in[2];   // [H,4H]
    const float* bias = (const float*)d_in[3];   // [4H]
    float* out = (float*)d_out;                  // [B,H] flat

    char* ws = (char*)d_ws;
    unsigned short* xbf   = (unsigned short*)(ws);               // 50,331,648 B
    unsigned short* wih_t = (unsigned short*)(ws + 50331648);    //  6,291,456
    unsigned short* whh_t = (unsigned short*)(ws + 56623104);    //  8,388,608
    unsigned short* hbf0  = (unsigned short*)(ws + 65011712);    //  4,194,304
    unsigned short* hbf1  = (unsigned short*)(ws + 69206016);    //  4,194,304
    float*          c     = (float*)(ws + 73400320);             //  8,388,608
    unsigned short* gx    = (unsigned short*)(ws + 81788928);    // 268,435,456
    // total 350,224,384 B <= ws_size

    int n4 = B_ * T_ * F_ / 4;
    hipLaunchKernelGGL(convert_x_kernel, dim3((n4 + 255) / 256), dim3(256), 0, stream,
                       x, xbf, n4);
    hipLaunchKernelGGL(transpose_w_kernel, dim3(G4_ / 32, F_ / 32), dim3(32, 8), 0, stream,
                       Wih, wih_t, F_, 0);
    hipLaunchKernelGGL(transpose_w_kernel, dim3(G4_ / 32, H_ / 32), dim3(32, 8), 0, stream,
                       Whh, whh_t, H_, 1);

    // all-timestep input projection (43% of FLOPs, fully parallel)
    hipLaunchKernelGGL(xgemm8_kernel, dim3(2048), dim3(512), 0, stream,
                       xbf, wih_t, gx);

    // t = 0: pure elementwise cell
    hipLaunchKernelGGL(cell0_kernel, dim3(B_ * H_ / 256), dim3(256), 0, stream,
                       gx, bias, c, hbf0);

    // t = 1..15: recurrent GEMM + fused cell, 2 blocks/CU
    for (int t = 1; t < T_; ++t) {
        unsigned short* hr = (t & 1) ? hbf0 : hbf1;
        unsigned short* hw = (t & 1) ? hbf1 : hbf0;
        hipLaunchKernelGGL(lstm_step6_kernel, dim3(1024), dim3(256), 0, stream,
                           hr, whh_t, gx, bias, c, hw, out, t, (t == T_ - 1) ? 1 : 0);
    }
}